// Round 19
// baseline (143.626 us; speedup 1.0000x reference)
//
#include <hip/hip_runtime.h>
#include <hip/hip_bf16.h>
#include <cstdint>

// Problem constants
#define NN   4
#define LL   4096      // 64*64
#define DD   18
#define CVV  128
#define CIN  256
#define CUU  10
#define HH   129
#define COO  10

typedef unsigned short ushort_t;
typedef __attribute__((ext_vector_type(8))) short short8v;   // 8 bf16 (4 VGPRs)
typedef __attribute__((ext_vector_type(4))) float f32x4;

// workspace layout (float offsets)
#define PT_OFF   ((size_t)0)          // pt bf16 [4][32 cg][4096 m][8 c] = 2097152 f
#define OP_OFF   ((size_t)2097152)    // u_pooled fp32 [4][10][4096] (qkval) THEN out_pre (combine+) = 163840 f
#define VAL_OFF  ((size_t)2260992)    // val bf16 = 1048576 f (later Lp[4][16384]+ypart[4][16384][10])
#define QT_OFF   ((size_t)3309568)    // qt bf16 [4][4096][32] = 262144 f (PRE-SCALED by log2e)
#define KT_OFF   ((size_t)3571712)    // kt bf16 tile-swizzled [4][64][4KB] = 262144 f
#define VT_OFF   ((size_t)3833856)    // vt bf16 tile-swizzled [4][128][8KB] = 1048576 f
#define VSC_OFF  ((size_t)4882432)
#define VSH_OFF  ((size_t)4882560)
#define S2_OFF   ((size_t)4882688)
#define SH2_OFF  ((size_t)4882704)
#define PART_OFF ((size_t)4882720)    // val-BN partials [256 blk][128 ch][2] = 65536 f
#define PART2_OFF ((size_t)4948256)   // out-BN partials [64][10][2] = 1280 f
#define KMAX_OFF ((size_t)4949536)    // kmax int bits [4][32]
// total ~4949664 f = 19.8 MB

#define LOG2E 1.44269504088896f

static __device__ __forceinline__ ushort_t f2bf(float x) {
    unsigned int u = __float_as_uint(x);
    unsigned int r = (u + 0x7fffu + ((u >> 16) & 1u)) >> 16;
    return (ushort_t)r;
}
static __device__ __forceinline__ float bf2f(ushort_t b) {
    return __uint_as_float(((unsigned int)b) << 16);
}
// hardware 2^x (v_exp_f32: D = 2^S0)
static __device__ __forceinline__ float exp2_hw(float x) {
    float r;
    asm("v_exp_f32 %0, %1" : "=v"(r) : "v"(x));
    return r;
}
// hardware packed f32x2 -> bf16x2 (RNE)
static __device__ __forceinline__ unsigned int cvtpk(float lo, float hi) {
    unsigned int r;
    asm("v_cvt_pk_bf16_f32 %0, %1, %2" : "=v"(r) : "v"(lo), "v"(hi));
    return r;
}

static __device__ __forceinline__ void gload16(const void* g, void* l) {
    __builtin_amdgcn_global_load_lds(
        (const __attribute__((address_space(1))) void*)g,
        (__attribute__((address_space(3))) void*)l, 16, 0, 0);
}

// ---------------- avg pool 3x3 s2 -> pt[n][cg][m][8c] bf16 (+ kmax zeroing) ----------------
__global__ __launch_bounds__(256) void pool_pt_kernel(const float* __restrict__ src,
                                                      ushort_t* __restrict__ pt,
                                                      int* __restrict__ kz) {
    if (kz != nullptr && blockIdx.x == 0 && threadIdx.x < 128) kz[threadIdx.x] = 0;
    int b = blockIdx.x;
    int rg = b & 15;
    int cg = (b >> 4) & 31;
    int n  = b >> 9;

    __shared__ float rows[8][9][132];
    const float* base = src + ((size_t)(n * CIN + cg * 8)) * (HH * HH) + (size_t)(rg * 8) * HH;
    for (int t = threadIdx.x; t < 8 * 9 * 132; t += 256) {
        int col = t % 132;
        int rr  = (t / 132) % 9;
        int ch  = t / (132 * 9);
        if (col < HH)
            rows[ch][rr][col] = base[(size_t)ch * (HH * HH) + (size_t)rr * HH + col];
    }
    __syncthreads();

    int row = threadIdx.x >> 6, ow = threadIdx.x & 63;
    int x = 2 * ow;
    union { short8v v; ushort_t s[8]; } pk;
    #pragma unroll
    for (int ch = 0; ch < 8; ++ch) {
        const float* r0 = rows[ch][2 * row];
        const float* r1 = rows[ch][2 * row + 1];
        const float* r2 = rows[ch][2 * row + 2];
        float sum = r0[x] + r0[x + 1] + r0[x + 2]
                  + r1[x] + r1[x + 1] + r1[x + 2]
                  + r2[x] + r2[x + 1] + r2[x + 2];
        pk.s[ch] = f2bf(sum * (1.0f / 9.0f));
    }
    int m = (rg * 4 + row) * 64 + ow;
    *(short8v*)(pt + (((size_t)(n * 32 + cg)) * 4096 + m) * 8) = pk.v;
}

// ---------------- avg pool 3x3 s2 for hu -> fp32 u[n][10][4096] ----------------
__global__ __launch_bounds__(256) void pool_u_kernel(const float* __restrict__ src,
                                                     float* __restrict__ dst) {
    int b = blockIdx.x;              // NN*CUU*16
    int plane = b >> 4;
    int rg = b & 15;
    __shared__ float rows[9][132];
    const float* sp = src + (size_t)plane * (HH * HH) + (size_t)(rg * 8) * HH;
    #pragma unroll
    for (int j = 0; j < 9; ++j) {
        if (threadIdx.x < HH) rows[j][threadIdx.x] = sp[(size_t)j * HH + threadIdx.x];
    }
    __syncthreads();
    int row = threadIdx.x >> 6, ow = threadIdx.x & 63;
    const float* r0 = rows[2 * row];
    const float* r1 = rows[2 * row + 1];
    const float* r2 = rows[2 * row + 2];
    int x = 2 * ow;
    float sum = r0[x] + r0[x + 1] + r0[x + 2]
              + r1[x] + r1[x + 1] + r1[x + 2]
              + r2[x] + r2[x + 1] + r2[x + 2];
    dst[(size_t)plane * 4096 + (size_t)(rg * 4 + row) * 64 + ow] = sum * (1.0f / 9.0f);
}

// ---------------- fat kernel: qk role (512 blocks x 32m, 8 c-partials) + MFMA val role ----------------
// grid 768; val role when blockIdx % 3 == 2.
__global__ __launch_bounds__(256, 2) void qkval5_kernel(const ushort_t* __restrict__ pt,
                                                        const float* __restrict__ u,
                                                        const float* __restrict__ Wq,
                                                        const float* __restrict__ Wk,
                                                        const float* __restrict__ Wv,
                                                        ushort_t* __restrict__ qt,
                                                        char* __restrict__ kt_c,
                                                        int* __restrict__ kmaxb,
                                                        ushort_t* __restrict__ val,
                                                        float* __restrict__ part) {
    __shared__ __align__(16) char smem[39936];   // qk: WkL[256][18] f32 (18432) + kacc[8][32][21] (21504)
    int tid = threadIdx.x;
    int bmod = blockIdx.x % 3;

    if (bmod != 2) {
        // ===================== QK role: 32 m, 8-way c-partials =====================
        float (*WkL)[DD] = (float(*)[DD])smem;
        float (*kacc)[32][21] = (float(*)[32][21])(smem + 18432);
        int bq = (blockIdx.x / 3) * 2 + bmod;    // 0..511
        int n  = bq >> 7;
        int mb = bq & 127;                       // 128 m-blocks of 32
        int w = tid >> 6;                        // cs quarter
        int lane = tid & 63;
        int mloc = lane & 31;
        int chh = lane >> 5;                     // c-half within quarter
        int m = mb * 32 + mloc;
        int hi = m >> 6, wi = m & 63;

        // stage Wk transposed: WkL[c][o] = Wk[o*264 + c]
        for (int e = tid; e < CIN * DD; e += 256) {
            int cc = e / DD, o = e - (e / DD) * DD;
            WkL[cc][o] = Wk[o * 264 + cc];
        }
        __syncthreads();

        float coord[8];
        coord[0] = wi * (2.0f / 64.0f) - 1.0f;
        coord[1] = hi * (2.0f / 64.0f) - 1.0f;
        coord[2] = (wi + 1) * (2.0f / 64.0f) - 1.0f;
        coord[3] = (hi + 1) * (2.0f / 64.0f) - 1.0f;
        coord[4] = 0.5f * (coord[0] + coord[2]);
        coord[5] = 0.5f * (coord[1] + coord[3]);
        coord[6] = 1.0f / 64.0f;
        coord[7] = 1.0f / 64.0f;

        // K partial over 32 c (this thread's quarter-half) via pt vector loads
        {
            float acc[DD];
            #pragma unroll
            for (int o = 0; o < DD; ++o) acc[o] = 0.0f;
            #pragma unroll
            for (int j = 0; j < 4; ++j) {
                int cgi = w * 8 + chh * 4 + j;
                union { short8v v; ushort_t s[8]; } ps;
                ps.v = *(const short8v*)(pt + (((size_t)(n * 32 + cgi)) * 4096 + m) * 8);
                #pragma unroll
                for (int i = 0; i < 8; ++i) {
                    float pv = bf2f(ps.s[i]);
                    const float* wr = WkL[cgi * 8 + i];
                    #pragma unroll
                    for (int o = 0; o < DD; ++o) acc[o] = fmaf(pv, wr[o], acc[o]);
                }
            }
            if (w == 3 && chh == 1) {
                #pragma unroll
                for (int j = 0; j < 8; ++j) {
                    float cv = coord[j];
                    #pragma unroll
                    for (int o = 0; o < DD; ++o) acc[o] = fmaf(cv, Wk[o * 264 + CIN + j], acc[o]);
                }
            }
            #pragma unroll
            for (int o = 0; o < DD; ++o) kacc[w * 2 + chh][mloc][o] = acc[o];
        }
        // Q on wave 0, lanes 0..31: reads PRE-POOLED u (L2-hot), PRE-SCALED by log2e
        if (w == 0 && chh == 0) {
            float acc[DD];
            #pragma unroll
            for (int o = 0; o < DD; ++o) acc[o] = 0.0f;
            const float* ub = u + ((size_t)(n * CUU)) * LL + m;
            #pragma unroll
            for (int cq = 0; cq < CUU; ++cq) {
                float uv = ub[(size_t)cq * LL];
                #pragma unroll
                for (int o = 0; o < DD; ++o) acc[o] = fmaf(uv, Wq[o * DD + cq], acc[o]);
            }
            #pragma unroll
            for (int j = 0; j < 8; ++j) {
                float cv = coord[j];
                #pragma unroll
                for (int o = 0; o < DD; ++o) acc[o] = fmaf(cv, Wq[o * DD + CUU + j], acc[o]);
            }
            union { short8v v[4]; ushort_t s[32]; } pk;
            #pragma unroll
            for (int o = 0; o < 32; ++o) pk.s[o] = (o < DD) ? f2bf(acc[o] * LOG2E) : (ushort_t)0;
            short8v* qrow = (short8v*)(qt + ((size_t)(n * LL) + m) * 32);
            #pragma unroll
            for (int j = 0; j < 4; ++j) qrow[j] = pk.v[j];
        }
        __syncthreads();
        // reduce 8 partials; threads 0..127: j = tid>>5 (16B chunk), mloc2 = tid&31
        if (tid < 128) {
            int j = tid >> 5;
            int mloc2 = tid & 31;
            int m2 = mb * 32 + mloc2;
            union { short8v v; ushort_t s[8]; } pk;
            #pragma unroll
            for (int i = 0; i < 8; ++i) {
                int o = j * 8 + i;
                float v = 0.0f;
                if (o < DD) {
                    v = kacc[0][mloc2][o] + kacc[1][mloc2][o] + kacc[2][mloc2][o] + kacc[3][mloc2][o]
                      + kacc[4][mloc2][o] + kacc[5][mloc2][o] + kacc[6][mloc2][o] + kacc[7][mloc2][o];
                }
                pk.s[i] = (o < DD) ? f2bf(v) : (ushort_t)0;
            }
            int ktile = m2 >> 6;
            int m64 = m2 & 63;
            int byte = ((m64 << 6) | (j << 4)) ^ (((m64 >> 1) & 7) << 4);
            *(short8v*)(kt_c + (size_t)n * 262144 + (size_t)ktile * 4096 + byte) = pk.v;

            int mb8[8];
            #pragma unroll
            for (int i = 0; i < 8; ++i) mb8[i] = (int)(pk.s[i] & 0x7fffu);
            #pragma unroll
            for (int off = 1; off < 32; off <<= 1) {
                #pragma unroll
                for (int i = 0; i < 8; ++i) {
                    int ov = __shfl_xor(mb8[i], off);
                    mb8[i] = max(mb8[i], ov);
                }
            }
            if (mloc2 == 0) {
                #pragma unroll
                for (int i = 0; i < 8; ++i)
                    atomicMax(&kmaxb[n * 32 + j * 8 + i], mb8[i] << 16);
            }
        }
    } else {
        // ===================== VAL role: MFMA GEMM 128ch x 64m per block =====================
        int b2 = blockIdx.x / 3;      // 0..255: n(4) x mb(64)
        int n  = b2 >> 6;
        int mb = b2 & 63;
        int m0 = mb * 64;
        int w = tid >> 6, lane = tid & 63, cl = lane & 15, g = lane >> 4;

        f32x4 acc[2][4];
        #pragma unroll
        for (int t = 0; t < 2; ++t)
            #pragma unroll
            for (int mt = 0; mt < 4; ++mt) acc[t][mt] = (f32x4){0.f, 0.f, 0.f, 0.f};

        #pragma unroll 2
        for (int kc = 0; kc < 8; ++kc) {
            short8v bfr[4];
            const ushort_t* pb2 = pt + (((size_t)(n * 32 + kc * 4 + g)) * 4096) * 8;
            #pragma unroll
            for (int mt = 0; mt < 4; ++mt)
                bfr[mt] = *(const short8v*)(pb2 + (size_t)(m0 + mt * 16 + cl) * 8);
            #pragma unroll
            for (int t = 0; t < 2; ++t) {
                int ch = (2 * w + t) * 16 + cl;
                const float* wr = Wv + (size_t)ch * CIN + kc * 32 + 8 * g;
                float4 wa = *(const float4*)wr;
                float4 wb = *(const float4*)(wr + 4);
                union { short8v v; ushort_t s[8]; } af;
                af.s[0] = f2bf(wa.x); af.s[1] = f2bf(wa.y); af.s[2] = f2bf(wa.z); af.s[3] = f2bf(wa.w);
                af.s[4] = f2bf(wb.x); af.s[5] = f2bf(wb.y); af.s[6] = f2bf(wb.z); af.s[7] = f2bf(wb.w);
                #pragma unroll
                for (int mt = 0; mt < 4; ++mt)
                    acc[t][mt] = __builtin_amdgcn_mfma_f32_16x16x32_bf16(af.v, bfr[mt], acc[t][mt], 0, 0, 0);
            }
        }

        #pragma unroll
        for (int t = 0; t < 2; ++t) {
            float s1[4] = {0.f, 0.f, 0.f, 0.f}, s2[4] = {0.f, 0.f, 0.f, 0.f};
            #pragma unroll
            for (int mt = 0; mt < 4; ++mt) {
                #pragma unroll
                for (int r = 0; r < 4; ++r) {
                    float v = acc[t][mt][r];
                    s1[r] += v;
                    s2[r] = fmaf(v, v, s2[r]);
                    int ch = (2 * w + t) * 16 + g * 4 + r;
                    val[((size_t)(n * CVV + ch)) * LL + m0 + mt * 16 + cl] = f2bf(v);
                }
            }
            #pragma unroll
            for (int off = 1; off < 16; off <<= 1) {
                #pragma unroll
                for (int r = 0; r < 4; ++r) {
                    s1[r] += __shfl_xor(s1[r], off);
                    s2[r] += __shfl_xor(s2[r], off);
                }
            }
            if (cl == 0) {
                #pragma unroll
                for (int r = 0; r < 4; ++r) {
                    int ch = (2 * w + t) * 16 + g * 4 + r;
                    size_t idx = (((size_t)b2) * CVV + ch) * 2;
                    part[idx]     = s1[r];
                    part[idx + 1] = s2[r];
                }
            }
        }
    }
}

// ---------------- BN1 finalize (part[256][128][2]) ----------------
__global__ __launch_bounds__(128) void bn_finalize_v2_kernel(const float* __restrict__ part,
                                                             const float* __restrict__ g,
                                                             const float* __restrict__ bta,
                                                             float* __restrict__ scale,
                                                             float* __restrict__ shift) {
    int ch = threadIdx.x;
    if (ch >= CVV) return;
    float s1 = 0.0f, s2 = 0.0f;
    for (int b = 0; b < 256; ++b) {
        size_t idx = ((size_t)b * CVV + ch) * 2;
        s1 += part[idx];
        s2 += part[idx + 1];
    }
    float mean = s1 * (1.0f / (NN * LL));
    float var = s2 * (1.0f / (NN * LL)) - mean * mean;
    float inv = rsqrtf(var + 1e-5f);
    float sc = g[ch] * inv;
    scale[ch] = sc;
    shift[ch] = bta[ch] - mean * sc;
}

// ---------------- apply BN + relu -> swizzled bf16 vt (32-m tiles), 8 m/thread ----------------
__global__ __launch_bounds__(256) void bn_apply2_kernel(const ushort_t* __restrict__ val,
                                                        const float* __restrict__ scale,
                                                        const float* __restrict__ shift,
                                                        char* __restrict__ vt_c) {
    int t = blockIdx.x * 256 + threadIdx.x;   // over NN*CVV*512
    int mq = t & 511;
    int ch = (t >> 9) & 127;
    int n = t >> 16;
    int m0 = mq * 8;
    short8v vs = *(const short8v*)(val + ((size_t)(n * CVV + ch)) * LL + m0);
    float sc = scale[ch], sh = shift[ch];
    union { short8v v; ushort_t s[8]; } pk;
    #pragma unroll
    for (int i = 0; i < 8; ++i)
        pk.s[i] = f2bf(fmaxf(fmaf(bf2f((ushort_t)vs[i]), sc, sh), 0.0f));
    int tile = m0 >> 5, mloc = m0 & 31;
    size_t byte = (size_t)n * 1048576 + (size_t)tile * 8192
                + (size_t)(((ch << 6) | (mloc << 1)) ^ ((ch & 7) << 4));
    *(short8v*)(vt_c + byte) = pk.v;
}

// ---------------- swapped-QK flash attention + fused projection, KVBLK=32, 4-way m-split ----------------
__global__ __launch_bounds__(256, 4) void attn_swz_kernel(const ushort_t* __restrict__ qt,
                                                          const char* __restrict__ kt_c,
                                                          const char* __restrict__ vt_c,
                                                          const int* __restrict__ kmaxb,
                                                          const float* __restrict__ Wp,
                                                          float* __restrict__ ypart,
                                                          float* __restrict__ Lp) {
    int orig = blockIdx.x;                       // 1024
    int xcd = orig & 7;
    int idx = orig >> 3;                         // 0..127
    int qb = idx >> 1;                           // 0..63
    int combo = xcd * 2 + (idx & 1);             // 0..15 XCD-pinned (n,sM)
    int n = combo >> 2;
    int sM = combo & 3;
    int T0 = sM * 32;                            // first 32-m tile (of 128)

    int tid = threadIdx.x;
    int w = tid >> 6, lane = tid & 63, c = lane & 15, g = lane >> 4;
    int l0w = qb * 64 + w * 16;

    __shared__ __align__(16) ushort_t K_t[2][1024];   // 2 x 2KB
    __shared__ __align__(16) ushort_t V_t[2][4096];   // 2 x 8KB
    __shared__ __align__(16) uint4 exch[4][64];       // 4KB, intra-wave P exchange
    __shared__ float Wpl[COO][CVV];                   // 5KB

    for (int i = tid; i < COO * CVV; i += 256) Wpl[i >> 7][i & 127] = Wp[i];

    const char* ktb = kt_c + (size_t)n * 262144;
    const char* vtb = vt_c + (size_t)n * 1048576;

    // Q as B-operand fragment (pre-scaled by log2e): row = c (q), k = g*8+i
    short8v qf = *(const short8v*)(qt + (((size_t)n * LL + l0w + c) << 5) + g * 8);
    int vxor = (c & 7) << 4;

    // analytic row-max bound (base-2 domain)
    float Mq = 0.0f;
    {
        const int* km = kmaxb + n * 32 + g * 8;
        #pragma unroll
        for (int i = 0; i < 8; ++i) {
            float kv = __int_as_float(km[i]);
            float aq = __uint_as_float(((unsigned int)((ushort_t)qf[i]) & 0x7fffu) << 16);
            Mq = fmaf(aq, kv, Mq);
        }
        Mq += __shfl_xor(Mq, 16);
        Mq += __shfl_xor(Mq, 32);
    }

    f32x4 O[8];
    #pragma unroll
    for (int i = 0; i < 8; ++i) O[i] = (f32x4){0.f, 0.f, 0.f, 0.f};
    float Lacc = 0.0f;

    int kby0, kby1;
    {
        int kr0 = c, kr1 = 16 + c;
        kby0 = ((kr0 << 6) | (g << 4)) ^ (((kr0 >> 1) & 7) << 4);
        kby1 = ((kr1 << 6) | (g << 4)) ^ (((kr1 >> 1) & 7) << 4);
    }
    int srcA = ((g & 1) << 5) + c;
    int toff = (g >> 1) * 8;

    {
        int T = T0;
        const char* ks = ktb + (size_t)(T >> 1) * 4096 + (T & 1) * 2048 + w * 1024 + lane * 16;
        if (w < 2) gload16(ks, (char*)K_t[0] + w * 1024);
        const char* vs = vtb + (size_t)T * 8192 + w * 2048 + lane * 16;
        gload16(vs, (char*)V_t[0] + w * 2048);
        gload16(vs + 1024, (char*)V_t[0] + w * 2048 + 1024);
    }
    __syncthreads();
    int buf = 0;
    for (int mt = 0; mt < 32; ++mt) {
        if (mt + 1 < 32) {
            int T = T0 + mt + 1;
            const char* ks = ktb + (size_t)(T >> 1) * 4096 + (T & 1) * 2048 + w * 1024 + lane * 16;
            if (w < 2) gload16(ks, (char*)K_t[buf ^ 1] + w * 1024);
            const char* vs = vtb + (size_t)T * 8192 + w * 2048 + lane * 16;
            gload16(vs, (char*)V_t[buf ^ 1] + w * 2048);
            gload16(vs + 1024, (char*)V_t[buf ^ 1] + w * 2048 + 1024);
        }
        // swapped QK: S = mfma(K, Q~) -> lane holds S~[m = 4g + r][q = c] (base-2 units)
        const char* kb = (const char*)K_t[buf];
        short8v kf0 = *(const short8v*)(kb + kby0);
        short8v kf1 = *(const short8v*)(kb + kby1);
        f32x4 S0 = __builtin_amdgcn_mfma_f32_16x16x32_bf16(kf0, qf, (f32x4){0.f,0.f,0.f,0.f}, 0, 0, 0);
        f32x4 S1 = __builtin_amdgcn_mfma_f32_16x16x32_bf16(kf1, qf, (f32x4){0.f,0.f,0.f,0.f}, 0, 0, 0);
        float p0[4], p1[4];
        #pragma unroll
        for (int r = 0; r < 4; ++r) {
            p0[r] = exp2_hw(S0[r] - Mq);
            p1[r] = exp2_hw(S1[r] - Mq);
            Lacc += p0[r] + p1[r];
        }
        exch[w][lane] = (uint4){ cvtpk(p0[0], p0[1]), cvtpk(p0[2], p0[3]),
                                 cvtpk(p1[0], p1[1]), cvtpk(p1[2], p1[3]) };
        const char* eb = (const char*)&exch[w][0];
        uint2 ua = *(const uint2*)(eb + srcA * 16 + toff);
        uint2 ub = *(const uint2*)(eb + (srcA + 16) * 16 + toff);
        union { unsigned int u[4]; short8v v; } pa;
        pa.u[0] = ua.x; pa.u[1] = ua.y; pa.u[2] = ub.x; pa.u[3] = ub.y;
        const char* vb = (const char*)V_t[buf];
        __builtin_amdgcn_s_setprio(1);
        #pragma unroll
        for (int ct = 0; ct < 8; ++ct) {
            int vby = (((ct * 16 + c) << 6) | (g << 4)) ^ vxor;
            short8v vf = *(const short8v*)(vb + vby);
            O[ct] = __builtin_amdgcn_mfma_f32_16x16x32_bf16(pa.v, vf, O[ct], 0, 0, 0);
        }
        __builtin_amdgcn_s_setprio(0);
        __syncthreads();
        buf ^= 1;
    }
    Lacc += __shfl_xor(Lacc, 16);
    Lacc += __shfl_xor(Lacc, 32);
    if (g == 0)
        Lp[sM * (NN * LL) + n * LL + l0w + c] = Lacc;

    float yp[COO][4];
    #pragma unroll
    for (int o = 0; o < COO; ++o)
        #pragma unroll
        for (int r = 0; r < 4; ++r) yp[o][r] = 0.0f;
    #pragma unroll
    for (int ct = 0; ct < 8; ++ct) {
        #pragma unroll
        for (int o = 0; o < COO; ++o) {
            float wv = Wpl[o][ct * 16 + c];
            #pragma unroll
            for (int r = 0; r < 4; ++r)
                yp[o][r] = fmaf(O[ct][r], wv, yp[o][r]);
        }
    }
    #pragma unroll
    for (int off = 1; off < 16; off <<= 1) {
        #pragma unroll
        for (int o = 0; o < COO; ++o)
            #pragma unroll
            for (int r = 0; r < 4; ++r)
                yp[o][r] += __shfl_xor(yp[o][r], off);
    }
    if (c == 0) {
        #pragma unroll
        for (int r = 0; r < 4; ++r) {
            size_t yrow = (size_t)(sM * (NN * LL) + n * LL + l0w + g * 4 + r);
            #pragma unroll
            for (int o = 0; o < COO; ++o)
                ypart[yrow * COO + o] = yp[o][r];
        }
    }
}

// ---------------- combine 4 m-splits + fused BN2 stat partials ----------------
__global__ __launch_bounds__(256) void combine4b_kernel(const float* __restrict__ ypart,
                                                        const float* __restrict__ Lp,
                                                        float* __restrict__ out_pre,
                                                        float* __restrict__ part2) {
    int idx = blockIdx.x * 256 + threadIdx.x;   // over NN*LL (64 blocks)
    int n = idx >> 12;
    int l = idx & 4095;
    int nl = n * LL + l;
    float inv = 1.0f / (Lp[nl] + Lp[16384 + nl] + Lp[2 * 16384 + nl] + Lp[3 * 16384 + nl]);
    const float* y0 = ypart + (size_t)nl * COO;
    const float* y1 = ypart + ((size_t)16384 + nl) * COO;
    const float* y2 = ypart + ((size_t)(2 * 16384) + nl) * COO;
    const float* y3 = ypart + ((size_t)(3 * 16384) + nl) * COO;
    float ov[COO];
    #pragma unroll
    for (int o = 0; o < COO; ++o) {
        ov[o] = (y0[o] + y1[o] + y2[o] + y3[o]) * inv;
        out_pre[((size_t)(n * COO + o)) * LL + l] = ov[o];
    }
    float p1[COO], p2[COO];
    #pragma unroll
    for (int o = 0; o < COO; ++o) { p1[o] = ov[o]; p2[o] = ov[o] * ov[o]; }
    #pragma unroll
    for (int off = 1; off < 64; off <<= 1) {
        #pragma unroll
        for (int o = 0; o < COO; ++o) {
            p1[o] += __shfl_xor(p1[o], off);
            p2[o] += __shfl_xor(p2[o], off);
        }
    }
    __shared__ float rs1[4][COO], rs2[4][COO];
    int w = threadIdx.x >> 6, lane = threadIdx.x & 63;
    if (lane == 0) {
        #pragma unroll
        for (int o = 0; o < COO; ++o) { rs1[w][o] = p1[o]; rs2[w][o] = p2[o]; }
    }
    __syncthreads();
    if (threadIdx.x < COO) {
        int o = threadIdx.x;
        float a = rs1[0][o] + rs1[1][o] + rs1[2][o] + rs1[3][o];
        float b = rs2[0][o] + rs2[1][o] + rs2[2][o] + rs2[3][o];
        part2[((size_t)blockIdx.x * COO + o) * 2]     = a;
        part2[((size_t)blockIdx.x * COO + o) * 2 + 1] = b;
    }
}

// ---------------- BN2 finalize ----------------
__global__ __launch_bounds__(64) void bn_finalize2_kernel(const float* __restrict__ part2,
                                                          const float* __restrict__ g,
                                                          const float* __restrict__ bta,
                                                          float* __restrict__ scale,
                                                          float* __restrict__ shift) {
    int ch = threadIdx.x;
    if (ch >= COO) return;
    float s1 = 0.0f, s2 = 0.0f;
    for (int b = 0; b < 64; ++b) {
        s1 += part2[((size_t)b * COO + ch) * 2];
        s2 += part2[((size_t)b * COO + ch) * 2 + 1];
    }
    float mean = s1 * (1.0f / (NN * LL));
    float var = s2 * (1.0f / (NN * LL)) - mean * mean;
    float inv = rsqrtf(var + 1e-5f);
    float sc = g[ch] * inv;
    scale[ch] = sc;
    shift[ch] = bta[ch] - mean * sc;
}

// ---------------- BN + relu + bilinear resize (align_corners=True) ----------------
__global__ __launch_bounds__(256) void resize_kernel(const float* __restrict__ out_pre,
                                                     const float* __restrict__ scale,
                                                     const float* __restrict__ shift,
                                                     float* __restrict__ out,
                                                     int total) {
    int idx = blockIdx.x * 256 + threadIdx.x;
    if (idx >= total) return;
    int ow = idx % HH;
    int t = idx / HH;
    int oh = t % HH;
    int t2 = t / HH;
    int o = t2 % COO;
    int n = t2 / COO;

    const float r = 63.0f / 128.0f;
    float y = oh * r;
    float x = ow * r;
    int y0 = (int)y;
    int x0 = (int)x;
    float wy = y - y0;
    float wx = x - x0;
    int y1 = min(y0 + 1, 63);
    int x1 = min(x0 + 1, 63);

    const float* base = out_pre + ((size_t)(n * COO + o)) * LL;
    float sc = scale[o], sh = shift[o];
    float v00 = fmaxf(fmaf(base[y0 * 64 + x0], sc, sh), 0.0f);
    float v01 = fmaxf(fmaf(base[y0 * 64 + x1], sc, sh), 0.0f);
    float v10 = fmaxf(fmaf(base[y1 * 64 + x0], sc, sh), 0.0f);
    float v11 = fmaxf(fmaf(base[y1 * 64 + x1], sc, sh), 0.0f);
    float top = v00 * (1.0f - wx) + v01 * wx;
    float bot = v10 * (1.0f - wx) + v11 * wx;
    out[idx] = top * (1.0f - wy) + bot * wy;
}

extern "C" void kernel_launch(void* const* d_in, const int* in_sizes, int n_in,
                              void* d_out, int out_size, void* d_ws, size_t ws_size,
                              hipStream_t stream) {
    (void)in_sizes; (void)n_in; (void)out_size; (void)ws_size;
    const float* p_fea = (const float*)d_in[0];
    const float* hu    = (const float*)d_in[1];
    const float* Wq    = (const float*)d_in[2];
    const float* Wk    = (const float*)d_in[3];
    const float* Wv    = (const float*)d_in[4];
    const float* g_v   = (const float*)d_in[5];
    const float* b_v   = (const float*)d_in[6];
    const float* Wp    = (const float*)d_in[7];
    const float* g_p   = (const float*)d_in[8];
    const float* b_p   = (const float*)d_in[9];

    float* ws = (float*)d_ws;
    ushort_t* ptb     = (ushort_t*)(ws + PT_OFF);
    float*    upool   = ws + OP_OFF;              // u pooled fp32 (dead after qkval5)
    float*    out_pre = ws + OP_OFF;              // alias: written only after attn
    ushort_t* valb    = (ushort_t*)(ws + VAL_OFF);
    ushort_t* qtb     = (ushort_t*)(ws + QT_OFF);
    char*     ktb     = (char*)(ws + KT_OFF);
    char*     vtb     = (char*)(ws + VT_OFF);
    float*    Lpart   = ws + VAL_OFF;             // alias: val dead after bn_apply2
    float*    ypart   = ws + VAL_OFF + 65536;     // [4][16384][10]
    float*    vscale  = ws + VSC_OFF;
    float*    vshift  = ws + VSH_OFF;
    float*    scale2  = ws + S2_OFF;
    float*    shift2  = ws + SH2_OFF;
    float*    part    = ws + PART_OFF;
    float*    part2   = ws + PART2_OFF;
    int*      kmaxb   = (int*)(ws + KMAX_OFF);

    pool_u_kernel<<<NN * CUU * 16, 256, 0, stream>>>(hu, upool);
    pool_pt_kernel<<<NN * 32 * 16, 256, 0, stream>>>(p_fea, ptb, kmaxb);
    qkval5_kernel<<<768, 256, 0, stream>>>(ptb, upool, Wq, Wk, Wv, qtb, ktb, kmaxb, valb, part);
    bn_finalize_v2_kernel<<<1, 128, 0, stream>>>(part, g_v, b_v, vscale, vshift);
    bn_apply2_kernel<<<(NN * CVV * 512) / 256, 256, 0, stream>>>(valb, vscale, vshift, vtb);
    attn_swz_kernel<<<1024, 256, 0, stream>>>(qtb, ktb, vtb, kmaxb, Wp, ypart, Lpart);
    combine4b_kernel<<<(NN * LL) / 256, 256, 0, stream>>>(ypart, Lpart, out_pre, part2);
    bn_finalize2_kernel<<<1, 64, 0, stream>>>(part2, g_p, b_p, scale2, shift2);
    {
        int total = NN * COO * HH * HH;
        resize_kernel<<<(total + 255) / 256, 256, 0, stream>>>(out_pre, scale2, shift2,
                                                               (float*)d_out, total);
    }
}

// Round 20
// 132.232 us; speedup vs baseline: 1.0862x; 1.0862x over previous
//
#include <hip/hip_runtime.h>
#include <hip/hip_bf16.h>
#include <cstdint>

// Problem constants
#define NN   4
#define LL   4096      // 64*64
#define DD   18
#define CVV  128
#define CIN  256
#define CUU  10
#define HH   129
#define COO  10

typedef unsigned short ushort_t;
typedef __attribute__((ext_vector_type(8))) short short8v;   // 8 bf16 (4 VGPRs)
typedef __attribute__((ext_vector_type(4))) float f32x4;

// workspace layout (float offsets)
#define PT_OFF   ((size_t)0)          // pt bf16 [4][32 cg][4096 m][8 c] = 2097152 f
#define OP_OFF   ((size_t)2097152)    // out_pre fp32 [4][10][4096] = 163840 f
#define VAL_OFF  ((size_t)2260992)    // val bf16 = 1048576 f (later Lp[4][16384]+ypart[4][16384][10])
#define QT_OFF   ((size_t)3309568)    // qt bf16 [4][4096][32] = 262144 f (PRE-SCALED by log2e)
#define KT_OFF   ((size_t)3571712)    // kt bf16 tile-swizzled [4][64][4KB] = 262144 f
#define VT_OFF   ((size_t)3833856)    // vt bf16 tile-swizzled [4][128][8KB] = 1048576 f
#define VSC_OFF  ((size_t)4882432)
#define VSH_OFF  ((size_t)4882560)
#define S2_OFF   ((size_t)4882688)
#define SH2_OFF  ((size_t)4882704)
#define PART_OFF ((size_t)4882720)    // val-BN partials [256 blk][128 ch][2] = 65536 f
#define PART2_OFF ((size_t)4948256)   // out-BN partials [64][10][2] = 1280 f
#define KMAX_OFF ((size_t)4949536)    // kmax int bits [4][32]
// total ~4949664 f = 19.8 MB

#define LOG2E 1.44269504088896f

static __device__ __forceinline__ ushort_t f2bf(float x) {
    unsigned int u = __float_as_uint(x);
    unsigned int r = (u + 0x7fffu + ((u >> 16) & 1u)) >> 16;
    return (ushort_t)r;
}
static __device__ __forceinline__ float bf2f(ushort_t b) {
    return __uint_as_float(((unsigned int)b) << 16);
}
// hardware 2^x (v_exp_f32: D = 2^S0)
static __device__ __forceinline__ float exp2_hw(float x) {
    float r;
    asm("v_exp_f32 %0, %1" : "=v"(r) : "v"(x));
    return r;
}
// hardware packed f32x2 -> bf16x2 (RNE)
static __device__ __forceinline__ unsigned int cvtpk(float lo, float hi) {
    unsigned int r;
    asm("v_cvt_pk_bf16_f32 %0, %1, %2" : "=v"(r) : "v"(lo), "v"(hi));
    return r;
}

static __device__ __forceinline__ void gload16(const void* g, void* l) {
    __builtin_amdgcn_global_load_lds(
        (const __attribute__((address_space(1))) void*)g,
        (__attribute__((address_space(3))) void*)l, 16, 0, 0);
}

// ---------------- avg pool 3x3 s2 -> pt[n][cg][m][8c] bf16, float4 staging (+ kmax zeroing) ----------------
__global__ __launch_bounds__(256) void pool_pt_kernel(const float* __restrict__ src,
                                                      ushort_t* __restrict__ pt,
                                                      int* __restrict__ kz) {
    if (kz != nullptr && blockIdx.x == 0 && threadIdx.x < 128) kz[threadIdx.x] = 0;
    int b = blockIdx.x;
    int rg = b & 15;
    int cg = (b >> 4) & 31;
    int n  = b >> 9;

    __shared__ float rows[8][9][132];
    const float* base = src + ((size_t)(n * CIN + cg * 8)) * (HH * HH) + (size_t)(rg * 8) * HH;
    // stage 8 channels x 9 rows x 129 cols using float4 chunks (32 x 16B + 1 scalar tail per row)
    #pragma unroll
    for (int rr = 0; rr < 9; ++rr) {
        for (int t = threadIdx.x; t < 264; t += 256) {
            int ch = t / 33;
            int c4 = t - ch * 33;
            const float* rp = base + (size_t)ch * (HH * HH) + (size_t)rr * HH;
            if (c4 < 32) {
                float4 v = *(const float4*)(rp + c4 * 4);   // dword-aligned multi-dword load
                *(float4*)&rows[ch][rr][c4 * 4] = v;
            } else {
                rows[ch][rr][128] = rp[128];
            }
        }
    }
    __syncthreads();

    int row = threadIdx.x >> 6, ow = threadIdx.x & 63;
    int x = 2 * ow;
    union { short8v v; ushort_t s[8]; } pk;
    #pragma unroll
    for (int ch = 0; ch < 8; ++ch) {
        const float* r0 = rows[ch][2 * row];
        const float* r1 = rows[ch][2 * row + 1];
        const float* r2 = rows[ch][2 * row + 2];
        float sum = r0[x] + r0[x + 1] + r0[x + 2]
                  + r1[x] + r1[x + 1] + r1[x + 2]
                  + r2[x] + r2[x + 1] + r2[x + 2];
        pk.s[ch] = f2bf(sum * (1.0f / 9.0f));
    }
    int m = (rg * 4 + row) * 64 + ow;
    *(short8v*)(pt + (((size_t)(n * 32 + cg)) * 4096 + m) * 8) = pk.v;
}

// ---------------- fat kernel: qk role (512 blocks x 32m, 8 c-partials) + MFMA val role ----------------
// grid 768; val role when blockIdx % 3 == 2.
__global__ __launch_bounds__(256, 2) void qkval4_kernel(const ushort_t* __restrict__ pt,
                                                        const float* __restrict__ hu,
                                                        const float* __restrict__ Wq,
                                                        const float* __restrict__ Wk,
                                                        const float* __restrict__ Wv,
                                                        ushort_t* __restrict__ qt,
                                                        char* __restrict__ kt_c,
                                                        int* __restrict__ kmaxb,
                                                        ushort_t* __restrict__ val,
                                                        float* __restrict__ part) {
    __shared__ __align__(16) char smem[39936];   // qk: WkL[256][18] f32 (18432) + kacc[8][32][21] (21504)
    int tid = threadIdx.x;
    int bmod = blockIdx.x % 3;

    if (bmod != 2) {
        // ===================== QK role: 32 m, 8-way c-partials =====================
        float (*WkL)[DD] = (float(*)[DD])smem;
        float (*kacc)[32][21] = (float(*)[32][21])(smem + 18432);
        int bq = (blockIdx.x / 3) * 2 + bmod;    // 0..511
        int n  = bq >> 7;
        int mb = bq & 127;                       // 128 m-blocks of 32
        int w = tid >> 6;                        // cs quarter
        int lane = tid & 63;
        int mloc = lane & 31;
        int chh = lane >> 5;                     // c-half within quarter
        int m = mb * 32 + mloc;
        int hi = m >> 6, wi = m & 63;

        // stage Wk transposed: WkL[c][o] = Wk[o*264 + c]
        for (int e = tid; e < CIN * DD; e += 256) {
            int cc = e / DD, o = e - (e / DD) * DD;
            WkL[cc][o] = Wk[o * 264 + cc];
        }
        __syncthreads();

        float coord[8];
        coord[0] = wi * (2.0f / 64.0f) - 1.0f;
        coord[1] = hi * (2.0f / 64.0f) - 1.0f;
        coord[2] = (wi + 1) * (2.0f / 64.0f) - 1.0f;
        coord[3] = (hi + 1) * (2.0f / 64.0f) - 1.0f;
        coord[4] = 0.5f * (coord[0] + coord[2]);
        coord[5] = 0.5f * (coord[1] + coord[3]);
        coord[6] = 1.0f / 64.0f;
        coord[7] = 1.0f / 64.0f;

        // K partial over 32 c (this thread's quarter-half) via pt vector loads
        {
            float acc[DD];
            #pragma unroll
            for (int o = 0; o < DD; ++o) acc[o] = 0.0f;
            #pragma unroll
            for (int j = 0; j < 4; ++j) {
                int cgi = w * 8 + chh * 4 + j;
                union { short8v v; ushort_t s[8]; } ps;
                ps.v = *(const short8v*)(pt + (((size_t)(n * 32 + cgi)) * 4096 + m) * 8);
                #pragma unroll
                for (int i = 0; i < 8; ++i) {
                    float pv = bf2f(ps.s[i]);
                    const float* wr = WkL[cgi * 8 + i];
                    #pragma unroll
                    for (int o = 0; o < DD; ++o) acc[o] = fmaf(pv, wr[o], acc[o]);
                }
            }
            if (w == 3 && chh == 1) {
                #pragma unroll
                for (int j = 0; j < 8; ++j) {
                    float cv = coord[j];
                    #pragma unroll
                    for (int o = 0; o < DD; ++o) acc[o] = fmaf(cv, Wk[o * 264 + CIN + j], acc[o]);
                }
            }
            #pragma unroll
            for (int o = 0; o < DD; ++o) kacc[w * 2 + chh][mloc][o] = acc[o];
        }
        // Q on wave 0, lanes 0..31 (one per m), inline hu pooling; Q PRE-SCALED by log2e
        if (w == 0 && chh == 0) {
            float acc[DD];
            #pragma unroll
            for (int o = 0; o < DD; ++o) acc[o] = 0.0f;
            const float* hub = hu + ((size_t)(n * CUU)) * (HH * HH) + (size_t)(2 * hi) * HH + 2 * wi;
            for (int cq = 0; cq < CUU; ++cq) {
                const float* s = hub + (size_t)cq * (HH * HH);
                float uv = (s[0] + s[1] + s[2]
                          + s[HH] + s[HH + 1] + s[HH + 2]
                          + s[2 * HH] + s[2 * HH + 1] + s[2 * HH + 2]) * (1.0f / 9.0f);
                #pragma unroll
                for (int o = 0; o < DD; ++o) acc[o] = fmaf(uv, Wq[o * DD + cq], acc[o]);
            }
            #pragma unroll
            for (int j = 0; j < 8; ++j) {
                float cv = coord[j];
                #pragma unroll
                for (int o = 0; o < DD; ++o) acc[o] = fmaf(cv, Wq[o * DD + CUU + j], acc[o]);
            }
            union { short8v v[4]; ushort_t s[32]; } pk;
            #pragma unroll
            for (int o = 0; o < 32; ++o) pk.s[o] = (o < DD) ? f2bf(acc[o] * LOG2E) : (ushort_t)0;
            short8v* qrow = (short8v*)(qt + ((size_t)(n * LL) + m) * 32);
            #pragma unroll
            for (int j = 0; j < 4; ++j) qrow[j] = pk.v[j];
        }
        __syncthreads();
        // reduce 8 partials; threads 0..127: j = tid>>5 (16B chunk), mloc2 = tid&31
        if (tid < 128) {
            int j = tid >> 5;
            int mloc2 = tid & 31;
            int m2 = mb * 32 + mloc2;
            union { short8v v; ushort_t s[8]; } pk;
            #pragma unroll
            for (int i = 0; i < 8; ++i) {
                int o = j * 8 + i;
                float v = 0.0f;
                if (o < DD) {
                    v = kacc[0][mloc2][o] + kacc[1][mloc2][o] + kacc[2][mloc2][o] + kacc[3][mloc2][o]
                      + kacc[4][mloc2][o] + kacc[5][mloc2][o] + kacc[6][mloc2][o] + kacc[7][mloc2][o];
                }
                pk.s[i] = (o < DD) ? f2bf(v) : (ushort_t)0;
            }
            int ktile = m2 >> 6;
            int m64 = m2 & 63;
            int byte = ((m64 << 6) | (j << 4)) ^ (((m64 >> 1) & 7) << 4);
            *(short8v*)(kt_c + (size_t)n * 262144 + (size_t)ktile * 4096 + byte) = pk.v;

            int mb8[8];
            #pragma unroll
            for (int i = 0; i < 8; ++i) mb8[i] = (int)(pk.s[i] & 0x7fffu);
            #pragma unroll
            for (int off = 1; off < 32; off <<= 1) {
                #pragma unroll
                for (int i = 0; i < 8; ++i) {
                    int ov = __shfl_xor(mb8[i], off);
                    mb8[i] = max(mb8[i], ov);
                }
            }
            if (mloc2 == 0) {
                #pragma unroll
                for (int i = 0; i < 8; ++i)
                    atomicMax(&kmaxb[n * 32 + j * 8 + i], mb8[i] << 16);
            }
        }
    } else {
        // ===================== VAL role: MFMA GEMM 128ch x 64m per block =====================
        int b2 = blockIdx.x / 3;      // 0..255: n(4) x mb(64)
        int n  = b2 >> 6;
        int mb = b2 & 63;
        int m0 = mb * 64;
        int w = tid >> 6, lane = tid & 63, cl = lane & 15, g = lane >> 4;

        f32x4 acc[2][4];
        #pragma unroll
        for (int t = 0; t < 2; ++t)
            #pragma unroll
            for (int mt = 0; mt < 4; ++mt) acc[t][mt] = (f32x4){0.f, 0.f, 0.f, 0.f};

        #pragma unroll 2
        for (int kc = 0; kc < 8; ++kc) {
            short8v bfr[4];
            const ushort_t* pb2 = pt + (((size_t)(n * 32 + kc * 4 + g)) * 4096) * 8;
            #pragma unroll
            for (int mt = 0; mt < 4; ++mt)
                bfr[mt] = *(const short8v*)(pb2 + (size_t)(m0 + mt * 16 + cl) * 8);
            #pragma unroll
            for (int t = 0; t < 2; ++t) {
                int ch = (2 * w + t) * 16 + cl;
                const float* wr = Wv + (size_t)ch * CIN + kc * 32 + 8 * g;
                float4 wa = *(const float4*)wr;
                float4 wb = *(const float4*)(wr + 4);
                union { short8v v; ushort_t s[8]; } af;
                af.s[0] = f2bf(wa.x); af.s[1] = f2bf(wa.y); af.s[2] = f2bf(wa.z); af.s[3] = f2bf(wa.w);
                af.s[4] = f2bf(wb.x); af.s[5] = f2bf(wb.y); af.s[6] = f2bf(wb.z); af.s[7] = f2bf(wb.w);
                #pragma unroll
                for (int mt = 0; mt < 4; ++mt)
                    acc[t][mt] = __builtin_amdgcn_mfma_f32_16x16x32_bf16(af.v, bfr[mt], acc[t][mt], 0, 0, 0);
            }
        }

        #pragma unroll
        for (int t = 0; t < 2; ++t) {
            float s1[4] = {0.f, 0.f, 0.f, 0.f}, s2[4] = {0.f, 0.f, 0.f, 0.f};
            #pragma unroll
            for (int mt = 0; mt < 4; ++mt) {
                #pragma unroll
                for (int r = 0; r < 4; ++r) {
                    float v = acc[t][mt][r];
                    s1[r] += v;
                    s2[r] = fmaf(v, v, s2[r]);
                    int ch = (2 * w + t) * 16 + g * 4 + r;
                    val[((size_t)(n * CVV + ch)) * LL + m0 + mt * 16 + cl] = f2bf(v);
                }
            }
            #pragma unroll
            for (int off = 1; off < 16; off <<= 1) {
                #pragma unroll
                for (int r = 0; r < 4; ++r) {
                    s1[r] += __shfl_xor(s1[r], off);
                    s2[r] += __shfl_xor(s2[r], off);
                }
            }
            if (cl == 0) {
                #pragma unroll
                for (int r = 0; r < 4; ++r) {
                    int ch = (2 * w + t) * 16 + g * 4 + r;
                    size_t idx = (((size_t)b2) * CVV + ch) * 2;
                    part[idx]     = s1[r];
                    part[idx + 1] = s2[r];
                }
            }
        }
    }
}

// ---------------- BN1 finalize (part[256][128][2]) ----------------
__global__ __launch_bounds__(128) void bn_finalize_v2_kernel(const float* __restrict__ part,
                                                             const float* __restrict__ g,
                                                             const float* __restrict__ bta,
                                                             float* __restrict__ scale,
                                                             float* __restrict__ shift) {
    int ch = threadIdx.x;
    if (ch >= CVV) return;
    float s1 = 0.0f, s2 = 0.0f;
    for (int b = 0; b < 256; ++b) {
        size_t idx = ((size_t)b * CVV + ch) * 2;
        s1 += part[idx];
        s2 += part[idx + 1];
    }
    float mean = s1 * (1.0f / (NN * LL));
    float var = s2 * (1.0f / (NN * LL)) - mean * mean;
    float inv = rsqrtf(var + 1e-5f);
    float sc = g[ch] * inv;
    scale[ch] = sc;
    shift[ch] = bta[ch] - mean * sc;
}

// ---------------- apply BN + relu -> swizzled bf16 vt (32-m tiles), 8 m/thread ----------------
__global__ __launch_bounds__(256) void bn_apply2_kernel(const ushort_t* __restrict__ val,
                                                        const float* __restrict__ scale,
                                                        const float* __restrict__ shift,
                                                        char* __restrict__ vt_c) {
    int t = blockIdx.x * 256 + threadIdx.x;   // over NN*CVV*512
    int mq = t & 511;
    int ch = (t >> 9) & 127;
    int n = t >> 16;
    int m0 = mq * 8;
    short8v vs = *(const short8v*)(val + ((size_t)(n * CVV + ch)) * LL + m0);
    float sc = scale[ch], sh = shift[ch];
    union { short8v v; ushort_t s[8]; } pk;
    #pragma unroll
    for (int i = 0; i < 8; ++i)
        pk.s[i] = f2bf(fmaxf(fmaf(bf2f((ushort_t)vs[i]), sc, sh), 0.0f));
    int tile = m0 >> 5, mloc = m0 & 31;
    size_t byte = (size_t)n * 1048576 + (size_t)tile * 8192
                + (size_t)(((ch << 6) | (mloc << 1)) ^ ((ch & 7) << 4));
    *(short8v*)(vt_c + byte) = pk.v;
}

// ---------------- swapped-QK flash attention + fused projection, KVBLK=32, 4-way m-split ----------------
__global__ __launch_bounds__(256, 4) void attn_swz_kernel(const ushort_t* __restrict__ qt,
                                                          const char* __restrict__ kt_c,
                                                          const char* __restrict__ vt_c,
                                                          const int* __restrict__ kmaxb,
                                                          const float* __restrict__ Wp,
                                                          float* __restrict__ ypart,
                                                          float* __restrict__ Lp) {
    int orig = blockIdx.x;                       // 1024
    int xcd = orig & 7;
    int idx = orig >> 3;                         // 0..127
    int qb = idx >> 1;                           // 0..63
    int combo = xcd * 2 + (idx & 1);             // 0..15 XCD-pinned (n,sM)
    int n = combo >> 2;
    int sM = combo & 3;
    int T0 = sM * 32;                            // first 32-m tile (of 128)

    int tid = threadIdx.x;
    int w = tid >> 6, lane = tid & 63, c = lane & 15, g = lane >> 4;
    int l0w = qb * 64 + w * 16;

    __shared__ __align__(16) ushort_t K_t[2][1024];   // 2 x 2KB
    __shared__ __align__(16) ushort_t V_t[2][4096];   // 2 x 8KB
    __shared__ __align__(16) uint4 exch[4][64];       // 4KB, intra-wave P exchange
    __shared__ float Wpl[COO][CVV];                   // 5KB

    for (int i = tid; i < COO * CVV; i += 256) Wpl[i >> 7][i & 127] = Wp[i];

    const char* ktb = kt_c + (size_t)n * 262144;
    const char* vtb = vt_c + (size_t)n * 1048576;

    // Q as B-operand fragment (pre-scaled by log2e): row = c (q), k = g*8+i
    short8v qf = *(const short8v*)(qt + (((size_t)n * LL + l0w + c) << 5) + g * 8);
    int vxor = (c & 7) << 4;

    // analytic row-max bound (base-2 domain)
    float Mq = 0.0f;
    {
        const int* km = kmaxb + n * 32 + g * 8;
        #pragma unroll
        for (int i = 0; i < 8; ++i) {
            float kv = __int_as_float(km[i]);
            float aq = __uint_as_float(((unsigned int)((ushort_t)qf[i]) & 0x7fffu) << 16);
            Mq = fmaf(aq, kv, Mq);
        }
        Mq += __shfl_xor(Mq, 16);
        Mq += __shfl_xor(Mq, 32);
    }

    f32x4 O[8];
    #pragma unroll
    for (int i = 0; i < 8; ++i) O[i] = (f32x4){0.f, 0.f, 0.f, 0.f};
    float Lacc = 0.0f;

    int kby0, kby1;
    {
        int kr0 = c, kr1 = 16 + c;
        kby0 = ((kr0 << 6) | (g << 4)) ^ (((kr0 >> 1) & 7) << 4);
        kby1 = ((kr1 << 6) | (g << 4)) ^ (((kr1 >> 1) & 7) << 4);
    }
    int srcA = ((g & 1) << 5) + c;
    int toff = (g >> 1) * 8;

    {
        int T = T0;
        const char* ks = ktb + (size_t)(T >> 1) * 4096 + (T & 1) * 2048 + w * 1024 + lane * 16;
        if (w < 2) gload16(ks, (char*)K_t[0] + w * 1024);
        const char* vs = vtb + (size_t)T * 8192 + w * 2048 + lane * 16;
        gload16(vs, (char*)V_t[0] + w * 2048);
        gload16(vs + 1024, (char*)V_t[0] + w * 2048 + 1024);
    }
    __syncthreads();
    int buf = 0;
    for (int mt = 0; mt < 32; ++mt) {
        if (mt + 1 < 32) {
            int T = T0 + mt + 1;
            const char* ks = ktb + (size_t)(T >> 1) * 4096 + (T & 1) * 2048 + w * 1024 + lane * 16;
            if (w < 2) gload16(ks, (char*)K_t[buf ^ 1] + w * 1024);
            const char* vs = vtb + (size_t)T * 8192 + w * 2048 + lane * 16;
            gload16(vs, (char*)V_t[buf ^ 1] + w * 2048);
            gload16(vs + 1024, (char*)V_t[buf ^ 1] + w * 2048 + 1024);
        }
        // swapped QK: S = mfma(K, Q~) -> lane holds S~[m = 4g + r][q = c] (base-2 units)
        const char* kb = (const char*)K_t[buf];
        short8v kf0 = *(const short8v*)(kb + kby0);
        short8v kf1 = *(const short8v*)(kb + kby1);
        f32x4 S0 = __builtin_amdgcn_mfma_f32_16x16x32_bf16(kf0, qf, (f32x4){0.f,0.f,0.f,0.f}, 0, 0, 0);
        f32x4 S1 = __builtin_amdgcn_mfma_f32_16x16x32_bf16(kf1, qf, (f32x4){0.f,0.f,0.f,0.f}, 0, 0, 0);
        float p0[4], p1[4];
        #pragma unroll
        for (int r = 0; r < 4; ++r) {
            p0[r] = exp2_hw(S0[r] - Mq);
            p1[r] = exp2_hw(S1[r] - Mq);
            Lacc += p0[r] + p1[r];
        }
        exch[w][lane] = (uint4){ cvtpk(p0[0], p0[1]), cvtpk(p0[2], p0[3]),
                                 cvtpk(p1[0], p1[1]), cvtpk(p1[2], p1[3]) };
        const char* eb = (const char*)&exch[w][0];
        uint2 ua = *(const uint2*)(eb + srcA * 16 + toff);
        uint2 ub = *(const uint2*)(eb + (srcA + 16) * 16 + toff);
        union { unsigned int u[4]; short8v v; } pa;
        pa.u[0] = ua.x; pa.u[1] = ua.y; pa.u[2] = ub.x; pa.u[3] = ub.y;
        const char* vb = (const char*)V_t[buf];
        __builtin_amdgcn_s_setprio(1);
        #pragma unroll
        for (int ct = 0; ct < 8; ++ct) {
            int vby = (((ct * 16 + c) << 6) | (g << 4)) ^ vxor;
            short8v vf = *(const short8v*)(vb + vby);
            O[ct] = __builtin_amdgcn_mfma_f32_16x16x32_bf16(pa.v, vf, O[ct], 0, 0, 0);
        }
        __builtin_amdgcn_s_setprio(0);
        __syncthreads();
        buf ^= 1;
    }
    Lacc += __shfl_xor(Lacc, 16);
    Lacc += __shfl_xor(Lacc, 32);
    if (g == 0)
        Lp[sM * (NN * LL) + n * LL + l0w + c] = Lacc;

    float yp[COO][4];
    #pragma unroll
    for (int o = 0; o < COO; ++o)
        #pragma unroll
        for (int r = 0; r < 4; ++r) yp[o][r] = 0.0f;
    #pragma unroll
    for (int ct = 0; ct < 8; ++ct) {
        #pragma unroll
        for (int o = 0; o < COO; ++o) {
            float wv = Wpl[o][ct * 16 + c];
            #pragma unroll
            for (int r = 0; r < 4; ++r)
                yp[o][r] = fmaf(O[ct][r], wv, yp[o][r]);
        }
    }
    #pragma unroll
    for (int off = 1; off < 16; off <<= 1) {
        #pragma unroll
        for (int o = 0; o < COO; ++o)
            #pragma unroll
            for (int r = 0; r < 4; ++r)
                yp[o][r] += __shfl_xor(yp[o][r], off);
    }
    if (c == 0) {
        #pragma unroll
        for (int r = 0; r < 4; ++r) {
            size_t yrow = (size_t)(sM * (NN * LL) + n * LL + l0w + g * 4 + r);
            #pragma unroll
            for (int o = 0; o < COO; ++o)
                ypart[yrow * COO + o] = yp[o][r];
        }
    }
}

// ---------------- combine 4 m-splits + fused BN2 stat partials ----------------
__global__ __launch_bounds__(256) void combine4b_kernel(const float* __restrict__ ypart,
                                                        const float* __restrict__ Lp,
                                                        float* __restrict__ out_pre,
                                                        float* __restrict__ part2) {
    int idx = blockIdx.x * 256 + threadIdx.x;   // over NN*LL (64 blocks)
    int n = idx >> 12;
    int l = idx & 4095;
    int nl = n * LL + l;
    float inv = 1.0f / (Lp[nl] + Lp[16384 + nl] + Lp[2 * 16384 + nl] + Lp[3 * 16384 + nl]);
    const float* y0 = ypart + (size_t)nl * COO;
    const float* y1 = ypart + ((size_t)16384 + nl) * COO;
    const float* y2 = ypart + ((size_t)(2 * 16384) + nl) * COO;
    const float* y3 = ypart + ((size_t)(3 * 16384) + nl) * COO;
    float ov[COO];
    #pragma unroll
    for (int o = 0; o < COO; ++o) {
        ov[o] = (y0[o] + y1[o] + y2[o] + y3[o]) * inv;
        out_pre[((size_t)(n * COO + o)) * LL + l] = ov[o];
    }
    float p1[COO], p2[COO];
    #pragma unroll
    for (int o = 0; o < COO; ++o) { p1[o] = ov[o]; p2[o] = ov[o] * ov[o]; }
    #pragma unroll
    for (int off = 1; off < 64; off <<= 1) {
        #pragma unroll
        for (int o = 0; o < COO; ++o) {
            p1[o] += __shfl_xor(p1[o], off);
            p2[o] += __shfl_xor(p2[o], off);
        }
    }
    __shared__ float rs1[4][COO], rs2[4][COO];
    int w = threadIdx.x >> 6, lane = threadIdx.x & 63;
    if (lane == 0) {
        #pragma unroll
        for (int o = 0; o < COO; ++o) { rs1[w][o] = p1[o]; rs2[w][o] = p2[o]; }
    }
    __syncthreads();
    if (threadIdx.x < COO) {
        int o = threadIdx.x;
        float a = rs1[0][o] + rs1[1][o] + rs1[2][o] + rs1[3][o];
        float b = rs2[0][o] + rs2[1][o] + rs2[2][o] + rs2[3][o];
        part2[((size_t)blockIdx.x * COO + o) * 2]     = a;
        part2[((size_t)blockIdx.x * COO + o) * 2 + 1] = b;
    }
}

// ---------------- BN2 finalize ----------------
__global__ __launch_bounds__(64) void bn_finalize2_kernel(const float* __restrict__ part2,
                                                          const float* __restrict__ g,
                                                          const float* __restrict__ bta,
                                                          float* __restrict__ scale,
                                                          float* __restrict__ shift) {
    int ch = threadIdx.x;
    if (ch >= COO) return;
    float s1 = 0.0f, s2 = 0.0f;
    for (int b = 0; b < 64; ++b) {
        s1 += part2[((size_t)b * COO + ch) * 2];
        s2 += part2[((size_t)b * COO + ch) * 2 + 1];
    }
    float mean = s1 * (1.0f / (NN * LL));
    float var = s2 * (1.0f / (NN * LL)) - mean * mean;
    float inv = rsqrtf(var + 1e-5f);
    float sc = g[ch] * inv;
    scale[ch] = sc;
    shift[ch] = bta[ch] - mean * sc;
}

// ---------------- BN + relu + bilinear resize (align_corners=True) ----------------
__global__ __launch_bounds__(256) void resize_kernel(const float* __restrict__ out_pre,
                                                     const float* __restrict__ scale,
                                                     const float* __restrict__ shift,
                                                     float* __restrict__ out,
                                                     int total) {
    int idx = blockIdx.x * 256 + threadIdx.x;
    if (idx >= total) return;
    int ow = idx % HH;
    int t = idx / HH;
    int oh = t % HH;
    int t2 = t / HH;
    int o = t2 % COO;
    int n = t2 / COO;

    const float r = 63.0f / 128.0f;
    float y = oh * r;
    float x = ow * r;
    int y0 = (int)y;
    int x0 = (int)x;
    float wy = y - y0;
    float wx = x - x0;
    int y1 = min(y0 + 1, 63);
    int x1 = min(x0 + 1, 63);

    const float* base = out_pre + ((size_t)(n * COO + o)) * LL;
    float sc = scale[o], sh = shift[o];
    float v00 = fmaxf(fmaf(base[y0 * 64 + x0], sc, sh), 0.0f);
    float v01 = fmaxf(fmaf(base[y0 * 64 + x1], sc, sh), 0.0f);
    float v10 = fmaxf(fmaf(base[y1 * 64 + x0], sc, sh), 0.0f);
    float v11 = fmaxf(fmaf(base[y1 * 64 + x1], sc, sh), 0.0f);
    float top = v00 * (1.0f - wx) + v01 * wx;
    float bot = v10 * (1.0f - wx) + v11 * wx;
    out[idx] = top * (1.0f - wy) + bot * wy;
}

extern "C" void kernel_launch(void* const* d_in, const int* in_sizes, int n_in,
                              void* d_out, int out_size, void* d_ws, size_t ws_size,
                              hipStream_t stream) {
    (void)in_sizes; (void)n_in; (void)out_size; (void)ws_size;
    const float* p_fea = (const float*)d_in[0];
    const float* hu    = (const float*)d_in[1];
    const float* Wq    = (const float*)d_in[2];
    const float* Wk    = (const float*)d_in[3];
    const float* Wv    = (const float*)d_in[4];
    const float* g_v   = (const float*)d_in[5];
    const float* b_v   = (const float*)d_in[6];
    const float* Wp    = (const float*)d_in[7];
    const float* g_p   = (const float*)d_in[8];
    const float* b_p   = (const float*)d_in[9];

    float* ws = (float*)d_ws;
    ushort_t* ptb     = (ushort_t*)(ws + PT_OFF);
    float*    out_pre = ws + OP_OFF;
    ushort_t* valb    = (ushort_t*)(ws + VAL_OFF);
    ushort_t* qtb     = (ushort_t*)(ws + QT_OFF);
    char*     ktb     = (char*)(ws + KT_OFF);
    char*     vtb     = (char*)(ws + VT_OFF);
    float*    Lpart   = ws + VAL_OFF;             // alias: val dead after bn_apply2
    float*    ypart   = ws + VAL_OFF + 65536;     // [4][16384][10]
    float*    vscale  = ws + VSC_OFF;
    float*    vshift  = ws + VSH_OFF;
    float*    scale2  = ws + S2_OFF;
    float*    shift2  = ws + SH2_OFF;
    float*    part    = ws + PART_OFF;
    float*    part2   = ws + PART2_OFF;
    int*      kmaxb   = (int*)(ws + KMAX_OFF);

    pool_pt_kernel<<<NN * 32 * 16, 256, 0, stream>>>(p_fea, ptb, kmaxb);
    qkval4_kernel<<<768, 256, 0, stream>>>(ptb, hu, Wq, Wk, Wv, qtb, ktb, kmaxb, valb, part);
    bn_finalize_v2_kernel<<<1, 128, 0, stream>>>(part, g_v, b_v, vscale, vshift);
    bn_apply2_kernel<<<(NN * CVV * 512) / 256, 256, 0, stream>>>(valb, vscale, vshift, vtb);
    attn_swz_kernel<<<1024, 256, 0, stream>>>(qtb, ktb, vtb, kmaxb, Wp, ypart, Lpart);
    combine4b_kernel<<<(NN * LL) / 256, 256, 0, stream>>>(ypart, Lpart, out_pre, part2);
    bn_finalize2_kernel<<<1, 64, 0, stream>>>(part2, g_p, b_p, scale2, shift2);
    {
        int total = NN * COO * HH * HH;
        resize_kernel<<<(total + 255) / 256, 256, 0, stream>>>(out_pre, scale2, shift2,
                                                               (float*)d_out, total);
    }
}